// Round 11
// baseline (601.943 us; speedup 1.0000x reference)
//
#include <hip/hip_runtime.h>
#include <hip/hip_cooperative_groups.h>

namespace cg = cooperative_groups;

constexpr int NN = 100000;   // nodes
constexpr int DI = 256;      // in features
constexpr int DO = 128;      // out features
constexpr int NE = 1600000;  // edges

constexpr int TILE = 2048;                        // edges per partition unit
constexpr int RCAP = 64;                          // per-row slots (deg~Pois(16); P(>64)~1e-13)

constexpr int NGB    = (NN + 63) / 64;            // 1563 gemm units
constexpr int NPB    = (NE + TILE - 1) / TILE;    // 782 part units
constexpr int NUNITS = NGB + NPB;                 // 2345
constexpr int GRID   = 1024;                      // 4 blocks/CU guaranteed co-resident

typedef __bf16 bf16x8 __attribute__((ext_vector_type(8)));
typedef float  f32x4  __attribute__((ext_vector_type(4)));

__device__ inline unsigned short f2bf(float f) {
    union { float f; unsigned u; } v; v.f = f;
    return (unsigned short)((v.u + 0x7FFF + ((v.u >> 16) & 1)) >> 16);
}
__device__ inline float bf2f(unsigned u16) {
    union { unsigned u; float f; } v; v.u = u16 << 16;
    return v.f;
}
__device__ inline void acc8(float* acc, const uint4& q, float w) {
    const unsigned* u = (const unsigned*)&q;
#pragma unroll
    for (int i = 0; i < 4; ++i) {
        acc[2 * i + 0] += w * bf2f(u[i] & 0xFFFF);
        acc[2 * i + 1] += w * bf2f(u[i] >> 16);
    }
}

// ---------------- single cooperative kernel -------------------------------
// R9 post-mortem: every round shows ~90-110us of inter-dispatch gap (sum of
// per-kernel dur_us ~260 vs 368 total; ~25us/launch). R10 failed with
// "container failed twice" -- same signature as R1/R2 which passed verbatim
// on resubmission (infra flake). Resubmitting hardened: kernel_launch checks
// the cooperative-launch return code and falls back to the proven R9
// three-kernel pipeline on error.
// Phases: 0) zero rcnt/wctr + wt transpose; grid.sync; 1) gemm+part units
// via dynamic work-stealing; grid.sync; 2) row gather.
// __launch_bounds__(256,4) -> VGPR<=128 -> 4 blocks/CU; LDS 27.7KB allows 5.
__global__ __launch_bounds__(256, 4)
void mega_kernel(const float* __restrict__ x, const float* __restrict__ mask,
                 const float* __restrict__ W, unsigned short* __restrict__ Wt,
                 unsigned short* __restrict__ h,
                 const int* __restrict__ erow, const int* __restrict__ ecol,
                 const float* __restrict__ ew, int* __restrict__ rcnt,
                 int2* __restrict__ ecsr, float* __restrict__ out,
                 int* __restrict__ wctr) {
    __shared__ union SMu {
        float t[32][33];                                                   // wt
        struct { unsigned short As[64][72]; unsigned short Bs[128][72]; } g;
    } sm;
    __shared__ int s_u;

    const int tid = threadIdx.x;
    const int bid = blockIdx.x;

    // ---------------- phase 0: zero rcnt + work counter, wt transpose ------
    for (int i = bid * 256 + tid; i < NN; i += GRID * 256) rcnt[i] = 0;
    if (bid == 0 && tid == 0) *wctr = 0;
    if (bid < 32) {
        const int tx = tid & 31, ty = tid >> 5;
        const int k0 = (bid >> 2) * 32, n0 = (bid & 3) * 32;
#pragma unroll
        for (int i = 0; i < 32; i += 8)
            sm.t[ty + i][tx] = W[(size_t)(k0 + ty + i) * DO + n0 + tx];
        __syncthreads();
#pragma unroll
        for (int i = 0; i < 32; i += 8)
            Wt[(size_t)(n0 + ty + i) * DI + k0 + tx] = f2bf(sm.t[tx][ty + i]);
    }
    cg::this_grid().sync();

    // ---------------- phase 1: gemm + part, dynamic work-stealing ----------
    for (;;) {
        if (tid == 0) s_u = atomicAdd(wctr, 1);
        __syncthreads();
        const int u = s_u;
        if (u >= NUNITS) break;
        const bool is_part = (u < 2 * NPB) && (u & 1);

        if (!is_part) {
            // ------------ gemm unit (proven 92 us baseline body) -----------
            const int gb   = (u < 2 * NPB) ? (u >> 1) : (u - NPB);
            const int lane = tid & 63;
            const int w    = tid >> 6;          // wave 0..3
            const int m0   = gb * 64;
            const int mw   = w * 16;            // wave's 16-row slice
            const int l15  = lane & 15;
            const int l4   = lane >> 4;

            f32x4 acc[8];
#pragma unroll
            for (int ct = 0; ct < 8; ++ct) acc[ct] = (f32x4){0.f, 0.f, 0.f, 0.f};

            const int lr = tid >> 4;         // 0..15: row within 16-row group
            const int lk = (tid & 15) * 4;   // 0..60: k offset (float4)

            float4 xv[4], mv[4];
            const float4 z4 = make_float4(0.f, 0.f, 0.f, 0.f);

            // prefetch kc = 0
#pragma unroll
            for (int p = 0; p < 4; ++p) {
                const int r = m0 + p * 16 + lr;
                if (r < NN) {
                    xv[p] = *(const float4*)(x    + (size_t)r * DI + lk);
                    mv[p] = *(const float4*)(mask + (size_t)r * DI + lk);
                } else { xv[p] = z4; mv[p] = z4; }
            }

            for (int kc = 0; kc < DI; kc += 64) {
                __syncthreads();   // prev MFMA done reading LDS
#pragma unroll
                for (int p = 0; p < 4; ++p) {
                    ushort4 pk;
                    pk.x = f2bf(xv[p].x * mv[p].x); pk.y = f2bf(xv[p].y * mv[p].y);
                    pk.z = f2bf(xv[p].z * mv[p].z); pk.w = f2bf(xv[p].w * mv[p].w);
                    *(ushort4*)&sm.g.As[p * 16 + lr][lk] = pk;
                }
                {
                    const int kl = (tid & 7) * 8;
#pragma unroll
                    for (int p = 0; p < 4; ++p) {
                        const int n = p * 32 + (tid >> 3);
                        *(uint4*)&sm.g.Bs[n][kl] =
                            *(const uint4*)(Wt + (size_t)n * DI + kc + kl);
                    }
                }
                if (kc + 64 < DI) {
#pragma unroll
                    for (int p = 0; p < 4; ++p) {
                        const int r = m0 + p * 16 + lr;
                        if (r < NN) {
                            xv[p] = *(const float4*)(x    + (size_t)r * DI + kc + 64 + lk);
                            mv[p] = *(const float4*)(mask + (size_t)r * DI + kc + 64 + lk);
                        } else { xv[p] = z4; mv[p] = z4; }
                    }
                }
                __syncthreads();
#pragma unroll
                for (int ks = 0; ks < 2; ++ks) {
                    const int ko = ks * 32 + l4 * 8;
                    const bf16x8 a0 = *(const bf16x8*)&sm.g.As[mw + l15][ko];
#pragma unroll
                    for (int ct = 0; ct < 8; ++ct) {
                        const bf16x8 b = *(const bf16x8*)&sm.g.Bs[ct * 16 + l15][ko];
                        acc[ct] = __builtin_amdgcn_mfma_f32_16x16x32_bf16(a0, b, acc[ct], 0, 0, 0);
                    }
                }
            }
            // epilogue: D[row = l4*4+reg][col = l15]
#pragma unroll
            for (int ct = 0; ct < 8; ++ct)
#pragma unroll
                for (int reg = 0; reg < 4; ++reg) {
                    const int row = m0 + mw + l4 * 4 + reg;
                    if (row < NN)
                        h[(size_t)row * DO + ct * 16 + l15] = f2bf(acc[ct][reg]);
                }
        } else {
            // ------------ part unit: direct per-row scatter, no LDS --------
            const int e0 = (u >> 1) * TILE;
#pragma unroll 4
            for (int k = 0; k < TILE; k += 256) {
                const int e = e0 + k + tid;
                if (e < NE) {
                    const int row = erow[e];
                    const int pos = atomicAdd(&rcnt[row], 1);
                    if (pos < RCAP) {
                        int2 v;
                        v.x = ecol[e];
                        v.y = __float_as_int(ew[e]);
                        ecsr[(size_t)row * RCAP + pos] = v;
                    }
                }
            }
        }
        __syncthreads();   // protect s_u and LDS reuse across units
    }
    cg::this_grid().sync();

    // ---------------- phase 2: row gather (8-deep pipelined) ---------------
    const int l16 = tid & 15, g = tid >> 4;
    const int ho  = l16 * 8;
    for (int r = bid * 16 + g; r < NN; r += GRID * 16) {
        int deg = rcnt[r];
        if (deg > RCAP) deg = RCAP;
        const int2* ep = ecsr + (size_t)r * RCAP;

        float acc[8];
#pragma unroll
        for (int i = 0; i < 8; ++i) acc[i] = 0.f;

        int j = 0;
        for (; j + 8 <= deg; j += 8) {
            const uint4 d0 = *(const uint4*)(ep + j);
            const uint4 d1 = *(const uint4*)(ep + j + 2);
            const uint4 d2 = *(const uint4*)(ep + j + 4);
            const uint4 d3 = *(const uint4*)(ep + j + 6);
            const uint4 q0 = *(const uint4*)(h + (size_t)d0.x * DO + ho);
            const uint4 q1 = *(const uint4*)(h + (size_t)d0.z * DO + ho);
            const uint4 q2 = *(const uint4*)(h + (size_t)d1.x * DO + ho);
            const uint4 q3 = *(const uint4*)(h + (size_t)d1.z * DO + ho);
            const uint4 q4 = *(const uint4*)(h + (size_t)d2.x * DO + ho);
            const uint4 q5 = *(const uint4*)(h + (size_t)d2.z * DO + ho);
            const uint4 q6 = *(const uint4*)(h + (size_t)d3.x * DO + ho);
            const uint4 q7 = *(const uint4*)(h + (size_t)d3.z * DO + ho);
            acc8(acc, q0, __int_as_float(d0.y));
            acc8(acc, q1, __int_as_float(d0.w));
            acc8(acc, q2, __int_as_float(d1.y));
            acc8(acc, q3, __int_as_float(d1.w));
            acc8(acc, q4, __int_as_float(d2.y));
            acc8(acc, q5, __int_as_float(d2.w));
            acc8(acc, q6, __int_as_float(d3.y));
            acc8(acc, q7, __int_as_float(d3.w));
        }
        for (; j + 2 <= deg; j += 2) {
            const int2 e0 = ep[j], e1 = ep[j + 1];
            const uint4 q0 = *(const uint4*)(h + (size_t)e0.x * DO + ho);
            const uint4 q1 = *(const uint4*)(h + (size_t)e1.x * DO + ho);
            acc8(acc, q0, __int_as_float(e0.y));
            acc8(acc, q1, __int_as_float(e1.y));
        }
        if (j < deg) {
            const int2 e0 = ep[j];
            const uint4 q0 = *(const uint4*)(h + (size_t)e0.x * DO + ho);
            acc8(acc, q0, __int_as_float(e0.y));
        }
        float* op = out + (size_t)r * DO + ho;
        *(float4*)(op + 0) = make_float4(fmaxf(acc[0], 0.f), fmaxf(acc[1], 0.f),
                                         fmaxf(acc[2], 0.f), fmaxf(acc[3], 0.f));
        *(float4*)(op + 4) = make_float4(fmaxf(acc[4], 0.f), fmaxf(acc[5], 0.f),
                                         fmaxf(acc[6], 0.f), fmaxf(acc[7], 0.f));
    }
}

// ================= fallback path (R9 pipeline, proven 367.7 us) =============
__global__ __launch_bounds__(256)
void wt_kernel(const float* __restrict__ W, unsigned short* __restrict__ Wt) {
    __shared__ float t[32][33];
    const int tx = threadIdx.x & 31, ty = threadIdx.x >> 5;
    const int k0 = (blockIdx.x >> 2) * 32, n0 = (blockIdx.x & 3) * 32;
#pragma unroll
    for (int i = 0; i < 32; i += 8)
        t[ty + i][tx] = W[(size_t)(k0 + ty + i) * DO + n0 + tx];
    __syncthreads();
#pragma unroll
    for (int i = 0; i < 32; i += 8)
        Wt[(size_t)(n0 + ty + i) * DI + k0 + tx] = f2bf(t[tx][ty + i]);
}

__global__ __launch_bounds__(256)
void gemm_part_kernel(const float* __restrict__ x, const float* __restrict__ mask,
                      const unsigned short* __restrict__ Wt,
                      unsigned short* __restrict__ h,
                      const int* __restrict__ erow, const int* __restrict__ ecol,
                      const float* __restrict__ ew, int* __restrict__ rcnt,
                      int2* __restrict__ ecsr) {
    __shared__ unsigned short As[64][72];
    __shared__ unsigned short Bs[128][72];

    const int bid = blockIdx.x;
    const bool is_part = (bid < 2 * NPB) && (bid & 1);

    if (!is_part) {
        const int gb   = (bid < 2 * NPB) ? (bid >> 1) : (bid - NPB);
        const int tid  = threadIdx.x;
        const int lane = tid & 63;
        const int w    = tid >> 6;
        const int m0   = gb * 64;
        const int mw   = w * 16;
        const int l15  = lane & 15;
        const int l4   = lane >> 4;

        f32x4 acc[8];
#pragma unroll
        for (int ct = 0; ct < 8; ++ct) acc[ct] = (f32x4){0.f, 0.f, 0.f, 0.f};

        const int lr = tid >> 4;
        const int lk = (tid & 15) * 4;

        float4 xv[4], mv[4];
        const float4 z4 = make_float4(0.f, 0.f, 0.f, 0.f);

#pragma unroll
        for (int p = 0; p < 4; ++p) {
            const int r = m0 + p * 16 + lr;
            if (r < NN) {
                xv[p] = *(const float4*)(x    + (size_t)r * DI + lk);
                mv[p] = *(const float4*)(mask + (size_t)r * DI + lk);
            } else { xv[p] = z4; mv[p] = z4; }
        }

        for (int kc = 0; kc < DI; kc += 64) {
            __syncthreads();
#pragma unroll
            for (int p = 0; p < 4; ++p) {
                ushort4 pk;
                pk.x = f2bf(xv[p].x * mv[p].x); pk.y = f2bf(xv[p].y * mv[p].y);
                pk.z = f2bf(xv[p].z * mv[p].z); pk.w = f2bf(xv[p].w * mv[p].w);
                *(ushort4*)&As[p * 16 + lr][lk] = pk;
            }
            {
                const int kl = (tid & 7) * 8;
#pragma unroll
                for (int p = 0; p < 4; ++p) {
                    const int n = p * 32 + (tid >> 3);
                    *(uint4*)&Bs[n][kl] =
                        *(const uint4*)(Wt + (size_t)n * DI + kc + kl);
                }
            }
            if (kc + 64 < DI) {
#pragma unroll
                for (int p = 0; p < 4; ++p) {
                    const int r = m0 + p * 16 + lr;
                    if (r < NN) {
                        xv[p] = *(const float4*)(x    + (size_t)r * DI + kc + 64 + lk);
                        mv[p] = *(const float4*)(mask + (size_t)r * DI + kc + 64 + lk);
                    } else { xv[p] = z4; mv[p] = z4; }
                }
            }
            __syncthreads();
#pragma unroll
            for (int ks = 0; ks < 2; ++ks) {
                const int ko = ks * 32 + l4 * 8;
                const bf16x8 a0 = *(const bf16x8*)&As[mw + l15][ko];
#pragma unroll
                for (int ct = 0; ct < 8; ++ct) {
                    const bf16x8 b = *(const bf16x8*)&Bs[ct * 16 + l15][ko];
                    acc[ct] = __builtin_amdgcn_mfma_f32_16x16x32_bf16(a0, b, acc[ct], 0, 0, 0);
                }
            }
        }
#pragma unroll
        for (int ct = 0; ct < 8; ++ct)
#pragma unroll
            for (int reg = 0; reg < 4; ++reg) {
                const int row = m0 + mw + l4 * 4 + reg;
                if (row < NN)
                    h[(size_t)row * DO + ct * 16 + l15] = f2bf(acc[ct][reg]);
            }
    } else {
        const int t  = threadIdx.x;
        const int e0 = (bid >> 1) * TILE;
#pragma unroll 4
        for (int k = 0; k < TILE; k += 256) {
            const int e = e0 + k + t;
            if (e < NE) {
                const int row = erow[e];
                const int pos = atomicAdd(&rcnt[row], 1);
                if (pos < RCAP) {
                    int2 v;
                    v.x = ecol[e];
                    v.y = __float_as_int(ew[e]);
                    ecsr[(size_t)row * RCAP + pos] = v;
                }
            }
        }
    }
}

__global__ __launch_bounds__(256)
void bgather_kernel(const unsigned short* __restrict__ h,
                    const int* __restrict__ rcnt,
                    const int2* __restrict__ ecsr, float* __restrict__ out) {
    const int t   = threadIdx.x;
    const int l16 = t & 15, g = t >> 4;
    const int gid0 = blockIdx.x * 16 + g;
    const int ngrp = gridDim.x * 16;
    const int ho   = l16 * 8;

    for (int r = gid0; r < NN; r += ngrp) {
        int deg = rcnt[r];
        if (deg > RCAP) deg = RCAP;
        const int2* ep = ecsr + (size_t)r * RCAP;

        float acc[8];
#pragma unroll
        for (int i = 0; i < 8; ++i) acc[i] = 0.f;

        int j = 0;
        for (; j + 8 <= deg; j += 8) {
            const uint4 d0 = *(const uint4*)(ep + j);
            const uint4 d1 = *(const uint4*)(ep + j + 2);
            const uint4 d2 = *(const uint4*)(ep + j + 4);
            const uint4 d3 = *(const uint4*)(ep + j + 6);
            const uint4 q0 = *(const uint4*)(h + (size_t)d0.x * DO + ho);
            const uint4 q1 = *(const uint4*)(h + (size_t)d0.z * DO + ho);
            const uint4 q2 = *(const uint4*)(h + (size_t)d1.x * DO + ho);
            const uint4 q3 = *(const uint4*)(h + (size_t)d1.z * DO + ho);
            const uint4 q4 = *(const uint4*)(h + (size_t)d2.x * DO + ho);
            const uint4 q5 = *(const uint4*)(h + (size_t)d2.z * DO + ho);
            const uint4 q6 = *(const uint4*)(h + (size_t)d3.x * DO + ho);
            const uint4 q7 = *(const uint4*)(h + (size_t)d3.z * DO + ho);
            acc8(acc, q0, __int_as_float(d0.y));
            acc8(acc, q1, __int_as_float(d0.w));
            acc8(acc, q2, __int_as_float(d1.y));
            acc8(acc, q3, __int_as_float(d1.w));
            acc8(acc, q4, __int_as_float(d2.y));
            acc8(acc, q5, __int_as_float(d2.w));
            acc8(acc, q6, __int_as_float(d3.y));
            acc8(acc, q7, __int_as_float(d3.w));
        }
        for (; j + 2 <= deg; j += 2) {
            const int2 e0 = ep[j], e1 = ep[j + 1];
            const uint4 q0 = *(const uint4*)(h + (size_t)e0.x * DO + ho);
            const uint4 q1 = *(const uint4*)(h + (size_t)e1.x * DO + ho);
            acc8(acc, q0, __int_as_float(e0.y));
            acc8(acc, q1, __int_as_float(e1.y));
        }
        if (j < deg) {
            const int2 e0 = ep[j];
            const uint4 q0 = *(const uint4*)(h + (size_t)e0.x * DO + ho);
            acc8(acc, q0, __int_as_float(e0.y));
        }
        float* op = out + (size_t)r * DO + ho;
        *(float4*)(op + 0) = make_float4(fmaxf(acc[0], 0.f), fmaxf(acc[1], 0.f),
                                         fmaxf(acc[2], 0.f), fmaxf(acc[3], 0.f));
        *(float4*)(op + 4) = make_float4(fmaxf(acc[4], 0.f), fmaxf(acc[5], 0.f),
                                         fmaxf(acc[6], 0.f), fmaxf(acc[7], 0.f));
    }
}

extern "C" void kernel_launch(void* const* d_in, const int* in_sizes, int n_in,
                              void* d_out, int out_size, void* d_ws, size_t ws_size,
                              hipStream_t stream) {
    const float* x    = (const float*)d_in[0];
    const float* mask = (const float*)d_in[1];
    const float* W    = (const float*)d_in[2];
    const int*   erow = (const int*)d_in[3];
    const int*   ecol = (const int*)d_in[4];
    const float* ew   = (const float*)d_in[5];
    float* out = (float*)d_out;

    char* p = (char*)d_ws;
    unsigned short* h  = (unsigned short*)p;  p += (size_t)NN * DO * 2;   // 25.6 MB
    unsigned short* Wt = (unsigned short*)p;  p += (size_t)DO * DI * 2;   // 64 KB
    int* rcnt = (int*)p;                      p += (size_t)NN * 4;        // 400 KB
    int* wctr = (int*)p;                      p += 256;                   // work counter
    int2* ecsr = (int2*)p;                    // NN*RCAP*8 = 51.2 MB

    void* args[] = {(void*)&x, (void*)&mask, (void*)&W, (void*)&Wt, (void*)&h,
                    (void*)&erow, (void*)&ecol, (void*)&ew, (void*)&rcnt,
                    (void*)&ecsr, (void*)&out, (void*)&wctr};
    hipError_t err = hipLaunchCooperativeKernel((const void*)mega_kernel,
                                                dim3(GRID), dim3(256),
                                                args, 0, stream);
    if (err != hipSuccess) {
        // Fallback: proven R9 three-kernel pipeline (367.7 us).
        hipMemsetAsync(rcnt, 0, (size_t)NN * sizeof(int), stream);
        wt_kernel<<<32, 256, 0, stream>>>(W, Wt);
        gemm_part_kernel<<<NGB + NPB, 256, 0, stream>>>(x, mask, Wt, h,
                                                        erow, ecol, ew, rcnt, ecsr);
        bgather_kernel<<<2048, 256, 0, stream>>>(h, rcnt, ecsr, out);
    }
}

// Round 12
// 359.457 us; speedup vs baseline: 1.6746x; 1.6746x over previous
//
#include <hip/hip_runtime.h>

constexpr int NN = 100000;   // nodes
constexpr int DI = 256;      // in features
constexpr int DO = 128;      // out features
constexpr int NE = 1600000;  // edges

constexpr int BROWS = 128;                        // rows per bucket
constexpr int NBK   = (NN + BROWS - 1) / BROWS;   // 782 buckets
constexpr int TILE  = 2048;                       // edges per partition block
constexpr int CAP   = 2688;                       // slots per bucket (mean 2046, sd ~45)

constexpr int NGB = (NN + 63) / 64;               // 1563 gemm blocks
constexpr int NPB = (NE + TILE - 1) / TILE;       // 782 part blocks

typedef __bf16 bf16x8 __attribute__((ext_vector_type(8)));
typedef float  f32x4  __attribute__((ext_vector_type(4)));

__device__ inline unsigned short f2bf(float f) {
    union { float f; unsigned u; } v; v.f = f;
    return (unsigned short)((v.u + 0x7FFF + ((v.u >> 16) & 1)) >> 16);
}
__device__ inline float bf2f(unsigned u16) {
    union { unsigned u; float f; } v; v.u = u16 << 16;
    return v.f;
}

// ---------------- W transpose: W[256][128] f32 -> Wt[128][256] bf16 ----------
__global__ __launch_bounds__(256)
void wt_kernel(const float* __restrict__ W, unsigned short* __restrict__ Wt) {
    __shared__ float t[32][33];
    const int tx = threadIdx.x & 31, ty = threadIdx.x >> 5;
    const int k0 = (blockIdx.x >> 2) * 32, n0 = (blockIdx.x & 3) * 32;
#pragma unroll
    for (int i = 0; i < 32; i += 8)
        t[ty + i][tx] = W[(size_t)(k0 + ty + i) * DO + n0 + tx];
    __syncthreads();
#pragma unroll
    for (int i = 0; i < 32; i += 8)
        Wt[(size_t)(n0 + ty + i) * DI + k0 + tx] = f2bf(t[tx][ty + i]);
}

// ---------------- fused GEMM + partition (block-range fusion) ---------------
// R11 post-mortem: cooperative mega-kernel FAILED (423us body; phase-2
// gather at half wave-residency ran 2.4x slower; the ~105us "gap" proved to
// be FIXED harness overhead, invariant to dispatch count -- cooperative
// launch even added ~70us host cost). The gather is concurrency-limited at
// the CU level (R9 depth-8 null, R11 wave-halving 2.4x) and standalone
// bgather already runs at the 32-wave/CU max. This file reverts to the
// best-proven R7 configuration (358.7us): blocks [0,NGB) gemm (proven 92us
// body), [NGB,NGB+NPB) part with LDS histogram buckets; LDS overlaid.
__global__ __launch_bounds__(256)
void gemm_part_kernel(const float* __restrict__ x, const float* __restrict__ mask,
                      const unsigned short* __restrict__ Wt,
                      unsigned short* __restrict__ h,
                      const int* __restrict__ erow, const int* __restrict__ ecol,
                      const float* __restrict__ ew, int* __restrict__ bcnt,
                      int2* __restrict__ csr) {
    __shared__ union {
        struct { unsigned short As[64][72]; unsigned short Bs[128][72]; } g; // 27648 B
        struct { int cnt[NBK]; int base[NBK]; } p;                           //  6256 B
    } sm;

    if (blockIdx.x < NGB) {
        // ---------------- gemm body (proven 92 us baseline, verbatim) ------
        const int tid  = threadIdx.x;
        const int lane = tid & 63;
        const int w    = tid >> 6;          // wave 0..3
        const int m0   = blockIdx.x * 64;
        const int mw   = w * 16;            // wave's 16-row slice
        const int l15  = lane & 15;
        const int l4   = lane >> 4;

        f32x4 acc[8];
#pragma unroll
        for (int ct = 0; ct < 8; ++ct) acc[ct] = (f32x4){0.f, 0.f, 0.f, 0.f};

        const int lr = tid >> 4;         // 0..15: row within 16-row group
        const int lk = (tid & 15) * 4;   // 0..60: k offset (float4)

        float4 xv[4], mv[4];
        const float4 z4 = make_float4(0.f, 0.f, 0.f, 0.f);

        // prefetch kc = 0
#pragma unroll
        for (int p = 0; p < 4; ++p) {
            const int r = m0 + p * 16 + lr;
            if (r < NN) {
                xv[p] = *(const float4*)(x    + (size_t)r * DI + lk);
                mv[p] = *(const float4*)(mask + (size_t)r * DI + lk);
            } else { xv[p] = z4; mv[p] = z4; }
        }

        for (int kc = 0; kc < DI; kc += 64) {
            __syncthreads();   // prev MFMA done reading LDS
            // store prefetched A (convert to bf16)
#pragma unroll
            for (int p = 0; p < 4; ++p) {
                ushort4 pk;
                pk.x = f2bf(xv[p].x * mv[p].x); pk.y = f2bf(xv[p].y * mv[p].y);
                pk.z = f2bf(xv[p].z * mv[p].z); pk.w = f2bf(xv[p].w * mv[p].w);
                *(ushort4*)&sm.g.As[p * 16 + lr][lk] = pk;
            }
            // stage B (L2-hot, 16 KB)
            {
                const int kl = (tid & 7) * 8;
#pragma unroll
                for (int p = 0; p < 4; ++p) {
                    const int n = p * 32 + (tid >> 3);
                    *(uint4*)&sm.g.Bs[n][kl] =
                        *(const uint4*)(Wt + (size_t)n * DI + kc + kl);
                }
            }
            // prefetch next K-tile (overlaps with MFMA below)
            if (kc + 64 < DI) {
#pragma unroll
                for (int p = 0; p < 4; ++p) {
                    const int r = m0 + p * 16 + lr;
                    if (r < NN) {
                        xv[p] = *(const float4*)(x    + (size_t)r * DI + kc + 64 + lk);
                        mv[p] = *(const float4*)(mask + (size_t)r * DI + kc + 64 + lk);
                    } else { xv[p] = z4; mv[p] = z4; }
                }
            }
            __syncthreads();
#pragma unroll
            for (int ks = 0; ks < 2; ++ks) {
                const int ko = ks * 32 + l4 * 8;
                const bf16x8 a0 = *(const bf16x8*)&sm.g.As[mw + l15][ko];
#pragma unroll
                for (int ct = 0; ct < 8; ++ct) {
                    const bf16x8 b = *(const bf16x8*)&sm.g.Bs[ct * 16 + l15][ko];
                    acc[ct] = __builtin_amdgcn_mfma_f32_16x16x32_bf16(a0, b, acc[ct], 0, 0, 0);
                }
            }
        }
        // epilogue: D[row = l4*4+reg][col = l15]
#pragma unroll
        for (int ct = 0; ct < 8; ++ct)
#pragma unroll
            for (int reg = 0; reg < 4; ++reg) {
                const int row = m0 + mw + l4 * 4 + reg;
                if (row < NN)
                    h[(size_t)row * DO + ct * 16 + l15] = f2bf(acc[ct][reg]);
            }
    } else {
        // ---------------- partition body -----------------------------------
        const int t  = threadIdx.x;
        const int e0 = (blockIdx.x - NGB) * TILE;
        for (int k = t; k < NBK; k += 256) sm.p.cnt[k] = 0;
        __syncthreads();
        for (int k = 0; k < TILE; k += 256) {
            const int e = e0 + k + t;
            if (e < NE) atomicAdd(&sm.p.cnt[erow[e] >> 7], 1);
        }
        __syncthreads();
        for (int k = t; k < NBK; k += 256) {
            const int c = sm.p.cnt[k];
            sm.p.base[k] = c ? atomicAdd(&bcnt[k], c) : 0;
            sm.p.cnt[k] = 0;
        }
        __syncthreads();
        for (int k = 0; k < TILE; k += 256) {
            const int e = e0 + k + t;
            if (e < NE) {
                const int row = erow[e];
                const int bk  = row >> 7;
                const int pos = atomicAdd(&sm.p.cnt[bk], 1);
                int2 v;
                v.x = ((row & 127) << 17) | ecol[e];   // col < 2^17
                v.y = __float_as_int(ew[e]);
                csr[(size_t)bk * CAP + sm.p.base[bk] + pos] = v;
            }
        }
    }
}

// ---------------- bucket gather: LDS counting sort + register gather --------
// 512 threads/block (grid fixed at 782 -> 3 blocks/CU; wider block = more
// resident waves for latency hiding on random h reads).
__global__ __launch_bounds__(512)
void bgather_kernel(const unsigned short* __restrict__ h,
                    const int* __restrict__ bcnt,
                    const int2* __restrict__ csr, float* __restrict__ out) {
    __shared__ int2 se[CAP];            // sorted edges
    __shared__ int  s_cnt[BROWS];       // histogram -> cursor
    __shared__ int  s_start[BROWS + 1];
    __shared__ int  wtot;
    const int b = blockIdx.x, t = threadIdx.x;
    const int n = bcnt[b];
    const int2* ebase = csr + (size_t)b * CAP;

    if (t < BROWS) s_cnt[t] = 0;
    __syncthreads();
    // pass 1: histogram by row-offset
    for (int j = t; j < n; j += 512)
        atomicAdd(&s_cnt[((unsigned)ebase[j].x) >> 17], 1);
    __syncthreads();
    // scan 128 bins
    const int lane = t & 63;
    int c = 0;
    if (t < BROWS) c = s_cnt[t];
    int v = c;
#pragma unroll
    for (int off = 1; off < 64; off <<= 1) {
        const int nn = __shfl_up(v, off, 64);
        if (lane >= off) v += nn;
    }
    if (t == 63) wtot = v;
    __syncthreads();
    if (t < BROWS) {
        const int excl = v - c + (t >= 64 ? wtot : 0);
        s_start[t] = excl;
        s_cnt[t]   = excl;   // reuse as scatter cursor
    }
    if (t == 0) s_start[BROWS] = n;
    __syncthreads();
    // pass 2: scatter into row-sorted order
    for (int j = t; j < n; j += 512) {
        const int2 cw  = ebase[j];
        const int  pos = atomicAdd(&s_cnt[((unsigned)cw.x) >> 17], 1);
        se[pos] = cw;
    }
    __syncthreads();

    // gather: 32 groups of 16 lanes; group g handles rows g, g+32, g+64, g+96
    const int l16 = t & 15, g = t >> 4;
    const int row0 = b * BROWS;
#pragma unroll
    for (int rp = 0; rp < 4; ++rp) {
        const int r  = rp * 32 + g;
        const int gr = row0 + r;
        const int rs = s_start[r], re = s_start[r + 1];
        float acc[8];
#pragma unroll
        for (int i = 0; i < 8; ++i) acc[i] = 0.f;
        int j = rs;
        for (; j + 2 <= re; j += 2) {
            const int2 cw0 = se[j], cw1 = se[j + 1];
            const float w0 = __int_as_float(cw0.y);
            const float w1 = __int_as_float(cw1.y);
            const uint4 q0 = *(const uint4*)(h + (size_t)(cw0.x & 0x1FFFF) * DO + l16 * 8);
            const uint4 q1 = *(const uint4*)(h + (size_t)(cw1.x & 0x1FFFF) * DO + l16 * 8);
            const unsigned* u0 = (const unsigned*)&q0;
            const unsigned* u1 = (const unsigned*)&q1;
#pragma unroll
            for (int i = 0; i < 4; ++i) {
                acc[2 * i + 0] += w0 * bf2f(u0[i] & 0xFFFF) + w1 * bf2f(u1[i] & 0xFFFF);
                acc[2 * i + 1] += w0 * bf2f(u0[i] >> 16)    + w1 * bf2f(u1[i] >> 16);
            }
        }
        if (j < re) {
            const int2 cw = se[j];
            const float w = __int_as_float(cw.y);
            const uint4 q = *(const uint4*)(h + (size_t)(cw.x & 0x1FFFF) * DO + l16 * 8);
            const unsigned* u = (const unsigned*)&q;
#pragma unroll
            for (int i = 0; i < 4; ++i) {
                acc[2 * i + 0] += w * bf2f(u[i] & 0xFFFF);
                acc[2 * i + 1] += w * bf2f(u[i] >> 16);
            }
        }
        if (gr < NN) {
            float* op = out + (size_t)gr * DO + l16 * 8;
            *(float4*)(op + 0) = make_float4(fmaxf(acc[0], 0.f), fmaxf(acc[1], 0.f),
                                             fmaxf(acc[2], 0.f), fmaxf(acc[3], 0.f));
            *(float4*)(op + 4) = make_float4(fmaxf(acc[4], 0.f), fmaxf(acc[5], 0.f),
                                             fmaxf(acc[6], 0.f), fmaxf(acc[7], 0.f));
        }
    }
}

extern "C" void kernel_launch(void* const* d_in, const int* in_sizes, int n_in,
                              void* d_out, int out_size, void* d_ws, size_t ws_size,
                              hipStream_t stream) {
    const float* x    = (const float*)d_in[0];
    const float* mask = (const float*)d_in[1];
    const float* W    = (const float*)d_in[2];
    const int*   erow = (const int*)d_in[3];
    const int*   ecol = (const int*)d_in[4];
    const float* ew   = (const float*)d_in[5];
    float* out = (float*)d_out;

    char* p = (char*)d_ws;
    unsigned short* h  = (unsigned short*)p;  p += (size_t)NN * DO * 2;   // 25.6 MB
    unsigned short* Wt = (unsigned short*)p;  p += (size_t)DO * DI * 2;   // 64 KB
    int* bcnt = (int*)p;                      p += 3200;
    int2* csr = (int2*)p;                     // NBK*CAP*8 = 16.8 MB

    hipMemsetAsync(bcnt, 0, NBK * sizeof(int), stream);

    wt_kernel<<<32, 256, 0, stream>>>(W, Wt);
    gemm_part_kernel<<<NGB + NPB, 256, 0, stream>>>(x, mask, Wt, h,
                                                    erow, ecol, ew, bcnt, csr);
    bgather_kernel<<<NBK, 512, 0, stream>>>(h, bcnt, csr, out);
}